// Round 9
// baseline (143.963 us; speedup 1.0000x reference)
//
#include <hip/hip_runtime.h>

typedef unsigned short u16;
typedef unsigned int u32;
typedef float v4f __attribute__((ext_vector_type(4)));
typedef __bf16 v8bf __attribute__((ext_vector_type(8)));

__device__ __forceinline__ u16 f2bf(float f) {
    union { float f; u32 u; } v; v.f = f;
    u32 r = v.u + 0x7fffu + ((v.u >> 16) & 1u);   // RNE
    return (u16)(r >> 16);
}
__device__ __forceinline__ u32 pk2(float lo, float hi) {
    return ((u32)f2bf(hi) << 16) | (u32)f2bf(lo);
}
// truncating pack of two f32 -> bf16x2 in ONE v_perm_b32
__device__ __forceinline__ u32 pk2t(float lo, float hi) {
    union { float f; u32 u; } a, b; a.f = hi; b.f = lo;
    return __builtin_amdgcn_perm(a.u, b.u, 0x07060302u);
}
__device__ __forceinline__ float bfLo(u32 p) {
    union { u32 u; float f; } v; v.u = p << 16; return v.f;
}
__device__ __forceinline__ float bfHi(u32 p) {
    union { u32 u; float f; } v; v.u = p & 0xffff0000u; return v.f;
}
__device__ __forceinline__ v4f zero4() { v4f z = {0.f, 0.f, 0.f, 0.f}; return z; }

// ---------------------------------------------------------------------------
// Kernel 0: W[k][h] fp32 -> WtF fragment layout (1 KB frags). grid 384, blk 64
// ---------------------------------------------------------------------------
__global__ __launch_bounds__(64) void prep_w(const float* __restrict__ Wk,
                                             const float* __restrict__ Wq,
                                             const float* __restrict__ Wv,
                                             u16* __restrict__ WtF) {
    const int f = blockIdx.x >> 5;
    const int ks = blockIdx.x & 31;
    const int lane = threadIdx.x;
    const int w = f >> 2;
    const float* W = (w == 0) ? Wk : ((w == 1) ? Wq : Wv);
    const int h = (f & 3) * 16 + (lane & 15);
    const int k0 = ks * 32 + (lane >> 4) * 8;
    u16 tmp[8];
#pragma unroll
    for (int j = 0; j < 8; ++j) tmp[j] = f2bf(W[(size_t)(k0 + j) * 64 + h]);
    *(uint4*)&WtF[((size_t)blockIdx.x * 64 + lane) * 8] = *(const uint4*)tmp;
}

// ---------------------------------------------------------------------------
// Kernel 1: qkv projection, K-split x4, x-in-registers. Outputs (ALL in MFMA
// fragment layout, 1 KB coalesced frags):
//  qgf : Q B-frag layout per 16-token group (pre-scaled by C^-0.5*log2e)
//  Kf  : [b][kt][ct][ks] A-frags for S^T
//  Vf  : [b][kt][ht][ks] A-frags for O^T
// grid 1024, block 256
// ---------------------------------------------------------------------------
__global__ __launch_bounds__(256, 4) void qkv_proj(const float* __restrict__ x,
                                                   const u16* __restrict__ WtF,
                                                   u16* __restrict__ qgf,
                                                   u16* __restrict__ Kf,
                                                   u16* __restrict__ Vf) {
    __shared__ v4f red[3][12][64];   // 36 KB; overlaid by T-tiles after reduce
    u16* Tk = (u16*)&red[0][0][0];   // [16][72]
    u16* Tq = Tk + 16 * 72;          // [16][72]
    u16* Tv = Tq + 16 * 72;          // [64][24]

    const int tid = threadIdx.x;
    const int lane = tid & 63;
    const int wv = tid >> 6;
    const int l15 = lane & 15, quad = lane >> 4;
    const int row0 = blockIdx.x * 16;

    v4f acc[12];
#pragma unroll
    for (int i = 0; i < 12; ++i) acc[i] = zero4();

    const float* xr = x + (size_t)(row0 + l15) * 1024 + wv * 256 + quad * 8;

    union { u32 u[4]; v8bf v; } af[8];
#pragma unroll
    for (int half = 0; half < 2; ++half) {
        float4 t[8];
#pragma unroll
        for (int i = 0; i < 8; ++i)
            t[i] = *(const float4*)(xr + half * 128 + (i >> 1) * 32 + (i & 1) * 4);
#pragma unroll
        for (int j = 0; j < 4; ++j) {
            int ks = half * 4 + j;
            af[ks].u[0] = pk2(t[2 * j].x, t[2 * j].y);
            af[ks].u[1] = pk2(t[2 * j].z, t[2 * j].w);
            af[ks].u[2] = pk2(t[2 * j + 1].x, t[2 * j + 1].y);
            af[ks].u[3] = pk2(t[2 * j + 1].z, t[2 * j + 1].w);
        }
    }

    const u16* wf0 = WtF + ((size_t)(wv * 8) * 64 + lane) * 8;
#pragma unroll
    for (int f = 0; f < 12; ++f) {
        const u16* wpf = wf0 + (size_t)f * 16384;
#pragma unroll
        for (int ks = 0; ks < 8; ++ks) {
            acc[f] = __builtin_amdgcn_mfma_f32_16x16x32_bf16(
                af[ks].v, *(const v8bf*)(wpf + ks * 512), acc[f], 0, 0, 0);
        }
    }

    if (wv > 0) {
#pragma unroll
        for (int f = 0; f < 12; ++f) red[wv - 1][f][lane] = acc[f];
    }
    __syncthreads();
    if (wv == 0) {
#pragma unroll
        for (int f = 0; f < 12; ++f) {
            acc[f] += red[0][f][lane];
            acc[f] += red[1][f][lane];
            acc[f] += red[2][f][lane];
        }
    }
    __syncthreads();
    if (wv == 0) {
        const float QSC = 0.04508422002778f;  // 2^-5 * log2(e)
#pragma unroll
        for (int ct = 0; ct < 4; ++ct)
#pragma unroll
            for (int r = 0; r < 4; ++r) {
                Tk[(quad * 4 + r) * 72 + ct * 16 + l15] = f2bf(acc[ct][r]);
                Tq[(quad * 4 + r) * 72 + ct * 16 + l15] = f2bf(acc[ct + 4][r] * QSC);
                Tv[(ct * 16 + l15) * 24 + quad * 4 + r] = f2bf(acc[ct + 8][r]);
            }
    }
    __syncthreads();

    const int b = row0 >> 12, t0 = row0 & 4095;
    const int kt = t0 >> 6, ctk = (t0 >> 4) & 3, ksv = (t0 >> 5) & 1;
    const int p0q = (t0 & 31) >> 3;
    const int g = blockIdx.x;   // global 16-token group index

    if (tid < 128) {
        // Q B-frag store (2 KB): frag f = tid>>6, lane ln = tid&63
        int f = tid >> 6, ln = tid & 63;
        *(uint4*)&qgf[((size_t)(g * 2 + f) * 64 + ln) * 8] =
            *(const uint4*)&Tq[(ln & 15) * 72 + f * 32 + (ln >> 4) * 8];
        // Vf frag store (2 KB)
        int ht = tid >> 5, sub = (tid >> 4) & 1, l15p = tid & 15;
        int lane2 = (p0q + sub) * 16 + l15p;
        size_t fb = ((((size_t)(b * 64 + kt) * 4 + ht) * 2 + ksv) * 64 + lane2) * 8;
        *(uint4*)&Vf[fb] = *(const uint4*)&Tv[(ht * 16 + l15p) * 24 + sub * 8];
    } else {
        // Kf frag store (2 KB)
        int lam = tid - 128;
        int ks = lam >> 6, ln = lam & 63;
        int l15p = ln & 15, qd = ln >> 4;
        size_t fb = ((((size_t)(b * 64 + kt) * 4 + ctk) * 2 + ks) * 64 + ln) * 8;
        *(uint4*)&Kf[fb] = *(const uint4*)&Tk[l15p * 72 + ks * 32 + qd * 8];
    }
}

// ---------------------------------------------------------------------------
// Kernel 2: attention partials. ZERO LDS, zero barriers; ALL loads (Q/K/V)
// are coalesced 1 KB frag loads. l_i via ones-MFMA. NO-MAX softmax.
// Partials stored bf16-packed (h, h+32) per u32 -> half the store traffic.
// grid (64 qtiles, MAXCH, 4 batch), block 128 (2 waves x 32 queries)
// ---------------------------------------------------------------------------
__global__ __launch_bounds__(128, 3) void attn_part(const u16* __restrict__ qgf,
                                                    const u16* __restrict__ Kf,
                                                    const u16* __restrict__ Vf,
                                                    u32* __restrict__ Opb,
                                                    float* __restrict__ ml,
                                                    int KC, int MAXCH) {
    const int a = blockIdx.x, c = blockIdx.y, b = blockIdx.z;
    if (c * KC > a) return;

    const int tid  = threadIdx.x;
    const int lane = tid & 63;
    const int wv   = tid >> 6;
    const int l15  = lane & 15;
    const int quad = lane >> 4;
    const int q0   = a * 64 + wv * 32;

    // Q B-frags: coalesced loads from frag layout
    const int g0 = (b * 4096 + q0) >> 4;
    v8bf qf[2][2];
#pragma unroll
    for (int st = 0; st < 2; ++st) {
#pragma unroll
        for (int f = 0; f < 2; ++f)
            qf[st][f] = *(const v8bf*)&qgf[((size_t)((g0 + st) * 2 + f) * 64 + lane) * 8];
    }

    union { u32 u[4]; v8bf v; } ones;
    ones.u[0] = ones.u[1] = ones.u[2] = ones.u[3] = 0x3F803F80u;  // bf16 1.0 x8

    v4f o[2][4], l5[2];
#pragma unroll
    for (int st = 0; st < 2; ++st) {
        l5[st] = zero4();
#pragma unroll
        for (int i = 0; i < 4; ++i) o[st][i] = zero4();
    }

    const int kt0 = c * KC;
    const int kt1 = (kt0 + KC < a + 1) ? (kt0 + KC) : (a + 1);

    for (int kt = kt0; kt < kt1; ++kt) {
        const size_t tb = ((size_t)(b * 64 + kt) * 4) * 2 * 512;
        const u16* kp = Kf + tb + lane * 8;
        const u16* vp = Vf + tb + lane * 8;

        v8bf ka[4][2], av[4][2];
#pragma unroll
        for (int ct = 0; ct < 4; ++ct) {
            ka[ct][0] = *(const v8bf*)(kp + (ct * 2 + 0) * 512);
            ka[ct][1] = *(const v8bf*)(kp + (ct * 2 + 1) * 512);
            av[ct][0] = *(const v8bf*)(vp + (ct * 2 + 0) * 512);
            av[ct][1] = *(const v8bf*)(vp + (ct * 2 + 1) * 512);
        }

#pragma unroll
        for (int st = 0; st < 2; ++st) {
            v4f s[4];
#pragma unroll
            for (int ct = 0; ct < 4; ++ct) {
                v4f t = zero4();
                t = __builtin_amdgcn_mfma_f32_16x16x32_bf16(ka[ct][0], qf[st][0], t, 0, 0, 0);
                t = __builtin_amdgcn_mfma_f32_16x16x32_bf16(ka[ct][1], qf[st][1], t, 0, 0, 0);
                s[ct] = t;
            }

            if (kt == a) {   // causal mask only on the diagonal tile
                const int queryg = q0 + st * 16 + l15;
                const int key0 = kt * 64 + quad * 4;
#pragma unroll
                for (int ct = 0; ct < 4; ++ct)
#pragma unroll
                    for (int r = 0; r < 4; ++r)
                        s[ct][r] = ((key0 + ct * 16 + r) > queryg) ? -1e30f : s[ct][r];
            }

            u32 pk[4][2];
#pragma unroll
            for (int ct = 0; ct < 4; ++ct) {
                float p0 = exp2f(s[ct][0]);
                float p1 = exp2f(s[ct][1]);
                float p2 = exp2f(s[ct][2]);
                float p3 = exp2f(s[ct][3]);
                pk[ct][0] = pk2t(p0, p1);
                pk[ct][1] = pk2t(p2, p3);
            }

            const int srcA = ((quad & 1) << 5) + l15;
            const int srcB = srcA + 16;
            const bool hi = (quad >= 2);
#pragma unroll
            for (int ks = 0; ks < 2; ++ks) {
                u32 g0a = (u32)__shfl((int)pk[ks * 2][0], srcA);
                u32 g0b = (u32)__shfl((int)pk[ks * 2 + 1][0], srcA);
                u32 g1a = (u32)__shfl((int)pk[ks * 2][1], srcA);
                u32 g1b = (u32)__shfl((int)pk[ks * 2 + 1][1], srcA);
                u32 g2a = (u32)__shfl((int)pk[ks * 2][0], srcB);
                u32 g2b = (u32)__shfl((int)pk[ks * 2 + 1][0], srcB);
                u32 g3a = (u32)__shfl((int)pk[ks * 2][1], srcB);
                u32 g3b = (u32)__shfl((int)pk[ks * 2 + 1][1], srcB);
                union { u32 u[4]; v8bf v; } pf;
                pf.u[0] = hi ? g0b : g0a;
                pf.u[1] = hi ? g1b : g1a;
                pf.u[2] = hi ? g2b : g2a;
                pf.u[3] = hi ? g3b : g3a;
#pragma unroll
                for (int ht = 0; ht < 4; ++ht)
                    o[st][ht] = __builtin_amdgcn_mfma_f32_16x16x32_bf16(
                        av[ht][ks], pf.v, o[st][ht], 0, 0, 0);
                l5[st] = __builtin_amdgcn_mfma_f32_16x16x32_bf16(
                    ones.v, pf.v, l5[st], 0, 0, 0);
            }
        }
    }

    // bf16-packed partial store: row rw = ht*16+quad*4+r holds h-pair (rw, rw+32)
    size_t pidx = ((size_t)b * 64 + a) * MAXCH + c;
    u32* op = Opb + pidx * 2048;
#pragma unroll
    for (int st = 0; st < 2; ++st) {
#pragma unroll
        for (int ht = 0; ht < 2; ++ht)
#pragma unroll
            for (int r = 0; r < 4; ++r)
                op[(ht * 16 + quad * 4 + r) * 64 + wv * 32 + st * 16 + l15] =
                    pk2t(o[st][ht][r], o[st][ht + 2][r]);
        if (quad == 0)
            ml[pidx * 64 + wv * 32 + st * 16 + l15] = l5[st][0];
    }
}

// ---------------------------------------------------------------------------
// Kernel 3: combine bf16-packed partials. grid (64, 4, 4), block 256;
// thread = (query=tid&63, h0 = hz*16 + (tid>>6)*4).
// ---------------------------------------------------------------------------
__global__ __launch_bounds__(256) void attn_combine(const u32* __restrict__ Opb,
                                                    const float* __restrict__ ml,
                                                    float* __restrict__ out,
                                                    int KC, int MAXCH) {
    const int a = blockIdx.x, b = blockIdx.y, hz = blockIdx.z;
    const int nch = a / KC + 1;
    const int tid = threadIdx.x;
    const int q = tid & 63, hq = tid >> 6;
    const int h0 = hz * 16 + hq * 4;
    const int rb = h0 & 31;          // packed row of this h-group
    const bool hi = (h0 >= 32);      // take hi half of the pair
    const size_t pbase = ((size_t)b * 64 + a) * MAXCH;

    float L = 0.f;
    float acc[4] = {0.f, 0.f, 0.f, 0.f};
    for (int c = 0; c < nch; ++c) {
        L += ml[(pbase + c) * 64 + q];
        const u32* op = Opb + (pbase + c) * 2048;
#pragma unroll
        for (int j = 0; j < 4; ++j) {
            u32 v = op[(rb + j) * 64 + q];
            acc[j] += hi ? bfHi(v) : bfLo(v);
        }
    }
    float inv = 1.f / L;
    float4 st = {acc[0] * inv, acc[1] * inv, acc[2] * inv, acc[3] * inv};
    *(float4*)&out[((size_t)b * 4096 + a * 64 + q) * 64 + h0] = st;
}

// ---------------------------------------------------------------------------
extern "C" void kernel_launch(void* const* d_in, const int* in_sizes, int n_in,
                              void* d_out, int out_size, void* d_ws, size_t ws_size,
                              hipStream_t stream) {
    const float* x  = (const float*)d_in[0];
    const float* Wk = (const float*)d_in[1];
    const float* Wq = (const float*)d_in[2];
    const float* Wv = (const float*)d_in[3];
    float* out = (float*)d_out;

    char* wsb = (char*)d_ws;
    u16* WtF = (u16*)wsb;                                  // 393216 B
    u16* qgf = (u16*)(wsb + 393216);                       // 2 MiB
    u16* Kf  = (u16*)(wsb + 393216 + 2097152);             // 2 MiB
    u16* Vf  = (u16*)(wsb + 393216 + 2 * 2097152);         // 2 MiB
    const size_t base = 393216 + 3 * 2097152;              // 6684672

    // finest split that fits: Opb (bf16-packed) + ml
    int KC = 4, MAXCH = 16;
    while (KC < 64 && base + (size_t)256 * MAXCH * (2048 * 4 + 256) > ws_size) {
        KC <<= 1; MAXCH >>= 1;
    }
    u32* Opb = (u32*)(wsb + base);
    float* ml = (float*)(wsb + base + (size_t)256 * MAXCH * 2048 * 4);

    prep_w<<<dim3(384), dim3(64), 0, stream>>>(Wk, Wq, Wv, WtF);
    qkv_proj<<<dim3(1024), dim3(256), 0, stream>>>(x, WtF, qgf, Kf, Vf);
    attn_part<<<dim3(64, MAXCH, 4), dim3(128), 0, stream>>>(qgf, Kf, Vf, Opb, ml, KC, MAXCH);
    attn_combine<<<dim3(64, 4, 4), dim3(256), 0, stream>>>(Opb, ml, out, KC, MAXCH);
}

// Round 10
// 143.330 us; speedup vs baseline: 1.0044x; 1.0044x over previous
//
#include <hip/hip_runtime.h>

typedef unsigned short u16;
typedef unsigned int u32;
typedef float v4f __attribute__((ext_vector_type(4)));
typedef __bf16 v8bf __attribute__((ext_vector_type(8)));

__device__ __forceinline__ u16 f2bf(float f) {
    union { float f; u32 u; } v; v.f = f;
    u32 r = v.u + 0x7fffu + ((v.u >> 16) & 1u);   // RNE
    return (u16)(r >> 16);
}
__device__ __forceinline__ u32 pk2(float lo, float hi) {
    return ((u32)f2bf(hi) << 16) | (u32)f2bf(lo);
}
// truncating pack of two f32 -> bf16x2 in ONE v_perm_b32
__device__ __forceinline__ u32 pk2t(float lo, float hi) {
    union { float f; u32 u; } a, b; a.f = hi; b.f = lo;
    return __builtin_amdgcn_perm(a.u, b.u, 0x07060302u);
}
__device__ __forceinline__ float bfLo(u32 p) {
    union { u32 u; float f; } v; v.u = p << 16; return v.f;
}
__device__ __forceinline__ float bfHi(u32 p) {
    union { u32 u; float f; } v; v.u = p & 0xffff0000u; return v.f;
}
__device__ __forceinline__ v4f zero4() { v4f z = {0.f, 0.f, 0.f, 0.f}; return z; }

// ---------------------------------------------------------------------------
// Kernel 0: W[k][h] fp32 -> WtF fragment layout (1 KB frags). grid 384, blk 64
// ---------------------------------------------------------------------------
__global__ __launch_bounds__(64) void prep_w(const float* __restrict__ Wk,
                                             const float* __restrict__ Wq,
                                             const float* __restrict__ Wv,
                                             u16* __restrict__ WtF) {
    const int f = blockIdx.x >> 5;
    const int ks = blockIdx.x & 31;
    const int lane = threadIdx.x;
    const int w = f >> 2;
    const float* W = (w == 0) ? Wk : ((w == 1) ? Wq : Wv);
    const int h = (f & 3) * 16 + (lane & 15);
    const int k0 = ks * 32 + (lane >> 4) * 8;
    u16 tmp[8];
#pragma unroll
    for (int j = 0; j < 8; ++j) tmp[j] = f2bf(W[(size_t)(k0 + j) * 64 + h]);
    *(uint4*)&WtF[((size_t)blockIdx.x * 64 + lane) * 8] = *(const uint4*)tmp;
}

// ---------------------------------------------------------------------------
// Kernel 1: qkv projection. 32-row blocks: each W B-frag feeds TWO row-half
// MFMAs -> W L2 traffic halves (402->201 MB) and MFMA:load = 2:1.
// Wave wv: 32 rows x 192 cols over K [wv*256, wv*256+256); x in registers
// (af[2][8]); LDS tree-reduce; fragment-layout outputs (qgf/Kf/Vf).
// grid 512, block 256, 2 waves/SIMD (VGPR cap 256; 72 KB LDS, 2 blocks/CU)
// ---------------------------------------------------------------------------
__global__ __launch_bounds__(256, 2) void qkv_proj(const float* __restrict__ x,
                                                   const u16* __restrict__ WtF,
                                                   u16* __restrict__ qgf,
                                                   u16* __restrict__ Kf,
                                                   u16* __restrict__ Vf) {
    __shared__ v4f red[3][24][64];   // 72 KB; overlaid by T-tiles after reduce
    u16* Tk = (u16*)&red[0][0][0];   // [32][72]
    u16* Tq = Tk + 32 * 72;          // [32][72]
    u16* Tv = Tq + 32 * 72;          // [64][40]  (h-major, 32 tokens + pad)

    const int tid = threadIdx.x;
    const int lane = tid & 63;
    const int wv = tid >> 6;
    const int l15 = lane & 15, quad = lane >> 4;
    const int row0 = blockIdx.x * 32;

    v4f acc[2][12];
#pragma unroll
    for (int rh = 0; rh < 2; ++rh)
#pragma unroll
        for (int i = 0; i < 12; ++i) acc[rh][i] = zero4();

    // preload x slice: 32 float4/lane in 4 batches of 8, convert to A-frags
    union { u32 u[4]; v8bf v; } af[2][8];
#pragma unroll
    for (int rh = 0; rh < 2; ++rh) {
        const float* xr = x + (size_t)(row0 + rh * 16 + l15) * 1024 + wv * 256 + quad * 8;
#pragma unroll
        for (int half = 0; half < 2; ++half) {
            float4 t[8];
#pragma unroll
            for (int i = 0; i < 8; ++i)
                t[i] = *(const float4*)(xr + half * 128 + (i >> 1) * 32 + (i & 1) * 4);
#pragma unroll
            for (int j = 0; j < 4; ++j) {
                int ks = half * 4 + j;
                af[rh][ks].u[0] = pk2(t[2 * j].x, t[2 * j].y);
                af[rh][ks].u[1] = pk2(t[2 * j].z, t[2 * j].w);
                af[rh][ks].u[2] = pk2(t[2 * j + 1].x, t[2 * j + 1].y);
                af[rh][ks].u[3] = pk2(t[2 * j + 1].z, t[2 * j + 1].w);
            }
        }
    }

    const u16* wf0 = WtF + ((size_t)(wv * 8) * 64 + lane) * 8;
#pragma unroll
    for (int f = 0; f < 12; ++f) {
        const u16* wpf = wf0 + (size_t)f * 16384;
#pragma unroll
        for (int ks = 0; ks < 8; ++ks) {
            v8bf bw = *(const v8bf*)(wpf + ks * 512);
            acc[0][f] = __builtin_amdgcn_mfma_f32_16x16x32_bf16(af[0][ks].v, bw,
                                                                acc[0][f], 0, 0, 0);
            acc[1][f] = __builtin_amdgcn_mfma_f32_16x16x32_bf16(af[1][ks].v, bw,
                                                                acc[1][f], 0, 0, 0);
        }
    }

    if (wv > 0) {
#pragma unroll
        for (int rh = 0; rh < 2; ++rh)
#pragma unroll
            for (int f = 0; f < 12; ++f) red[wv - 1][rh * 12 + f][lane] = acc[rh][f];
    }
    __syncthreads();
    if (wv == 0) {
#pragma unroll
        for (int rh = 0; rh < 2; ++rh)
#pragma unroll
            for (int f = 0; f < 12; ++f) {
                acc[rh][f] += red[0][rh * 12 + f][lane];
                acc[rh][f] += red[1][rh * 12 + f][lane];
                acc[rh][f] += red[2][rh * 12 + f][lane];
            }
    }
    __syncthreads();   // all red reads done before T-tile overlay writes
    if (wv == 0) {
        const float QSC = 0.04508422002778f;  // 2^-5 * log2(e)
#pragma unroll
        for (int rh = 0; rh < 2; ++rh)
#pragma unroll
            for (int ct = 0; ct < 4; ++ct)
#pragma unroll
                for (int r = 0; r < 4; ++r) {
                    int tok = rh * 16 + quad * 4 + r;
                    Tk[tok * 72 + ct * 16 + l15] = f2bf(acc[rh][ct][r]);
                    Tq[tok * 72 + ct * 16 + l15] = f2bf(acc[rh][ct + 4][r] * QSC);
                    Tv[(ct * 16 + l15) * 40 + tok] = f2bf(acc[rh][ct + 8][r]);
                }
    }
    __syncthreads();

    const int b = row0 >> 12, t0 = row0 & 4095;
    const int kt = t0 >> 6, ct0 = (t0 >> 4) & 3, ksv = (t0 >> 5) & 1;
    const int ln = tid & 63, l15p = ln & 15, qd = ln >> 4;

    // Q B-frag store (4 KB): gi = token-16 group, fi = frag
    {
        int gi = tid >> 7, fi = (tid >> 6) & 1;
        *(uint4*)&qgf[((size_t)((blockIdx.x * 2 + gi) * 2 + fi) * 64 + ln) * 8] =
            *(const uint4*)&Tq[(gi * 16 + l15p) * 72 + fi * 32 + qd * 8];
    }
    // Kf frag store (4 KB): 2 ct x 2 ks frags
    {
        int cti = tid >> 7, ks = (tid >> 6) & 1;
        size_t fb = ((((size_t)(b * 64 + kt) * 4 + ct0 + cti) * 2 + ks) * 64 + ln) * 8;
        *(uint4*)&Kf[fb] = *(const uint4*)&Tk[(cti * 16 + l15p) * 72 + ks * 32 + qd * 8];
    }
    // Vf frag store (4 KB): 4 ht frags (full 32-key half ksv)
    {
        int ht = tid >> 6;
        size_t fb = ((((size_t)(b * 64 + kt) * 4 + ht) * 2 + ksv) * 64 + ln) * 8;
        *(uint4*)&Vf[fb] = *(const uint4*)&Tv[(ht * 16 + l15p) * 40 + qd * 8];
    }
}

// ---------------------------------------------------------------------------
// Kernel 2: attention partials. ZERO LDS, zero barriers; ALL loads (Q/K/V)
// are coalesced 1 KB frag loads. l_i via ones-MFMA. NO-MAX softmax.
// Partials stored bf16-packed (h, h+32) per u32.
// grid (64 qtiles, MAXCH, 4 batch), block 128 (2 waves x 32 queries)
// ---------------------------------------------------------------------------
__global__ __launch_bounds__(128, 3) void attn_part(const u16* __restrict__ qgf,
                                                    const u16* __restrict__ Kf,
                                                    const u16* __restrict__ Vf,
                                                    u32* __restrict__ Opb,
                                                    float* __restrict__ ml,
                                                    int KC, int MAXCH) {
    const int a = blockIdx.x, c = blockIdx.y, b = blockIdx.z;
    if (c * KC > a) return;

    const int tid  = threadIdx.x;
    const int lane = tid & 63;
    const int wv   = tid >> 6;
    const int l15  = lane & 15;
    const int quad = lane >> 4;
    const int q0   = a * 64 + wv * 32;

    const int g0 = (b * 4096 + q0) >> 4;
    v8bf qf[2][2];
#pragma unroll
    for (int st = 0; st < 2; ++st) {
#pragma unroll
        for (int f = 0; f < 2; ++f)
            qf[st][f] = *(const v8bf*)&qgf[((size_t)((g0 + st) * 2 + f) * 64 + lane) * 8];
    }

    union { u32 u[4]; v8bf v; } ones;
    ones.u[0] = ones.u[1] = ones.u[2] = ones.u[3] = 0x3F803F80u;  // bf16 1.0 x8

    v4f o[2][4], l5[2];
#pragma unroll
    for (int st = 0; st < 2; ++st) {
        l5[st] = zero4();
#pragma unroll
        for (int i = 0; i < 4; ++i) o[st][i] = zero4();
    }

    const int kt0 = c * KC;
    const int kt1 = (kt0 + KC < a + 1) ? (kt0 + KC) : (a + 1);

    for (int kt = kt0; kt < kt1; ++kt) {
        const size_t tb = ((size_t)(b * 64 + kt) * 4) * 2 * 512;
        const u16* kp = Kf + tb + lane * 8;
        const u16* vp = Vf + tb + lane * 8;

        v8bf ka[4][2], av[4][2];
#pragma unroll
        for (int ct = 0; ct < 4; ++ct) {
            ka[ct][0] = *(const v8bf*)(kp + (ct * 2 + 0) * 512);
            ka[ct][1] = *(const v8bf*)(kp + (ct * 2 + 1) * 512);
            av[ct][0] = *(const v8bf*)(vp + (ct * 2 + 0) * 512);
            av[ct][1] = *(const v8bf*)(vp + (ct * 2 + 1) * 512);
        }

#pragma unroll
        for (int st = 0; st < 2; ++st) {
            v4f s[4];
#pragma unroll
            for (int ct = 0; ct < 4; ++ct) {
                v4f t = zero4();
                t = __builtin_amdgcn_mfma_f32_16x16x32_bf16(ka[ct][0], qf[st][0], t, 0, 0, 0);
                t = __builtin_amdgcn_mfma_f32_16x16x32_bf16(ka[ct][1], qf[st][1], t, 0, 0, 0);
                s[ct] = t;
            }

            if (kt == a) {   // causal mask only on the diagonal tile
                const int queryg = q0 + st * 16 + l15;
                const int key0 = kt * 64 + quad * 4;
#pragma unroll
                for (int ct = 0; ct < 4; ++ct)
#pragma unroll
                    for (int r = 0; r < 4; ++r)
                        s[ct][r] = ((key0 + ct * 16 + r) > queryg) ? -1e30f : s[ct][r];
            }

            u32 pk[4][2];
#pragma unroll
            for (int ct = 0; ct < 4; ++ct) {
                float p0 = exp2f(s[ct][0]);
                float p1 = exp2f(s[ct][1]);
                float p2 = exp2f(s[ct][2]);
                float p3 = exp2f(s[ct][3]);
                pk[ct][0] = pk2t(p0, p1);
                pk[ct][1] = pk2t(p2, p3);
            }

            const int srcA = ((quad & 1) << 5) + l15;
            const int srcB = srcA + 16;
            const bool hi = (quad >= 2);
#pragma unroll
            for (int ks = 0; ks < 2; ++ks) {
                u32 g0a = (u32)__shfl((int)pk[ks * 2][0], srcA);
                u32 g0b = (u32)__shfl((int)pk[ks * 2 + 1][0], srcA);
                u32 g1a = (u32)__shfl((int)pk[ks * 2][1], srcA);
                u32 g1b = (u32)__shfl((int)pk[ks * 2 + 1][1], srcA);
                u32 g2a = (u32)__shfl((int)pk[ks * 2][0], srcB);
                u32 g2b = (u32)__shfl((int)pk[ks * 2 + 1][0], srcB);
                u32 g3a = (u32)__shfl((int)pk[ks * 2][1], srcB);
                u32 g3b = (u32)__shfl((int)pk[ks * 2 + 1][1], srcB);
                union { u32 u[4]; v8bf v; } pf;
                pf.u[0] = hi ? g0b : g0a;
                pf.u[1] = hi ? g1b : g1a;
                pf.u[2] = hi ? g2b : g2a;
                pf.u[3] = hi ? g3b : g3a;
#pragma unroll
                for (int ht = 0; ht < 4; ++ht)
                    o[st][ht] = __builtin_amdgcn_mfma_f32_16x16x32_bf16(
                        av[ht][ks], pf.v, o[st][ht], 0, 0, 0);
                l5[st] = __builtin_amdgcn_mfma_f32_16x16x32_bf16(
                    ones.v, pf.v, l5[st], 0, 0, 0);
            }
        }
    }

    size_t pidx = ((size_t)b * 64 + a) * MAXCH + c;
    u32* op = Opb + pidx * 2048;
#pragma unroll
    for (int st = 0; st < 2; ++st) {
#pragma unroll
        for (int ht = 0; ht < 2; ++ht)
#pragma unroll
            for (int r = 0; r < 4; ++r)
                op[(ht * 16 + quad * 4 + r) * 64 + wv * 32 + st * 16 + l15] =
                    pk2t(o[st][ht][r], o[st][ht + 2][r]);
        if (quad == 0)
            ml[pidx * 64 + wv * 32 + st * 16 + l15] = l5[st][0];
    }
}

// ---------------------------------------------------------------------------
// Kernel 3: combine bf16-packed partials. grid (64, 4, 4), block 256;
// thread = (query=tid&63, h0 = hz*16 + (tid>>6)*4).
// ---------------------------------------------------------------------------
__global__ __launch_bounds__(256) void attn_combine(const u32* __restrict__ Opb,
                                                    const float* __restrict__ ml,
                                                    float* __restrict__ out,
                                                    int KC, int MAXCH) {
    const int a = blockIdx.x, b = blockIdx.y, hz = blockIdx.z;
    const int nch = a / KC + 1;
    const int tid = threadIdx.x;
    const int q = tid & 63, hq = tid >> 6;
    const int h0 = hz * 16 + hq * 4;
    const int rb = h0 & 31;
    const bool hi = (h0 >= 32);
    const size_t pbase = ((size_t)b * 64 + a) * MAXCH;

    float L = 0.f;
    float acc[4] = {0.f, 0.f, 0.f, 0.f};
    for (int c = 0; c < nch; ++c) {
        L += ml[(pbase + c) * 64 + q];
        const u32* op = Opb + (pbase + c) * 2048;
#pragma unroll
        for (int j = 0; j < 4; ++j) {
            u32 v = op[(rb + j) * 64 + q];
            acc[j] += hi ? bfHi(v) : bfLo(v);
        }
    }
    float inv = 1.f / L;
    float4 st = {acc[0] * inv, acc[1] * inv, acc[2] * inv, acc[3] * inv};
    *(float4*)&out[((size_t)b * 4096 + a * 64 + q) * 64 + h0] = st;
}

// ---------------------------------------------------------------------------
extern "C" void kernel_launch(void* const* d_in, const int* in_sizes, int n_in,
                              void* d_out, int out_size, void* d_ws, size_t ws_size,
                              hipStream_t stream) {
    const float* x  = (const float*)d_in[0];
    const float* Wk = (const float*)d_in[1];
    const float* Wq = (const float*)d_in[2];
    const float* Wv = (const float*)d_in[3];
    float* out = (float*)d_out;

    char* wsb = (char*)d_ws;
    u16* WtF = (u16*)wsb;                                  // 393216 B
    u16* qgf = (u16*)(wsb + 393216);                       // 2 MiB
    u16* Kf  = (u16*)(wsb + 393216 + 2097152);             // 2 MiB
    u16* Vf  = (u16*)(wsb + 393216 + 2 * 2097152);         // 2 MiB
    const size_t base = 393216 + 3 * 2097152;              // 6684672

    int KC = 4, MAXCH = 16;
    while (KC < 64 && base + (size_t)256 * MAXCH * (2048 * 4 + 256) > ws_size) {
        KC <<= 1; MAXCH >>= 1;
    }
    u32* Opb = (u32*)(wsb + base);
    float* ml = (float*)(wsb + base + (size_t)256 * MAXCH * 2048 * 4);

    prep_w<<<dim3(384), dim3(64), 0, stream>>>(Wk, Wq, Wv, WtF);
    qkv_proj<<<dim3(512), dim3(256), 0, stream>>>(x, WtF, qgf, Kf, Vf);
    attn_part<<<dim3(64, MAXCH, 4), dim3(128), 0, stream>>>(qgf, Kf, Vf, Opb, ml, KC, MAXCH);
    attn_combine<<<dim3(64, 4, 4), dim3(256), 0, stream>>>(Opb, ml, out, KC, MAXCH);
}